// Round 13
// baseline (260.417 us; speedup 1.0000x reference)
//
#include <hip/hip_runtime.h>

// Problem constants (from reference setup_inputs)
#define B_  4
#define O_  32
#define C_  32
#define H_  32
#define W_  32
#define P_  5
#define T_  288        // C*3*3
#define PIX (H_ * W_)  // 1024
#define EPSF 1e-6f

#define NCH 2                 // input channels per block
#define CG  (C_ / NCH)        // 16 channel-groups
#define NO  2                 // output channels per block
#define OG  (O_ / NO)         // 16 o-groups
#define NB  2                 // batch images per block
#define BG  (B_ / NB)         // 2 batch-groups

// Per-entry table layout (16 floats, float4 quads):
//   q0 = inv_k = 1/(p[k+1]-p[k]+EPS) (k=0..3); q1 = -p[k]*inv_k;
//   q2 = v[k+1]-v[k]; q3.x = v[0]
#define ENT (NO * NCH * 9)        // 36 entries per block
#define TABF (ENT * 16)           // 576 floats

// x slab: NB batches x NCH channels, 34x34 halo, row stride 35 (bank pad).
#define XROW 34
#define XSTR 35
#define XS_PER_CH (XROW * XSTR)    // 1190
#define NSTAGE (NB * NCH * XROW * XROW) // 4624 elements to stage

__global__ __launch_bounds__(256, 2) void pw_conv(
    const float* __restrict__ x, const float* __restrict__ pos,
    const float* __restrict__ val, float* __restrict__ part)
{
    __shared__ float xs[NB * NCH * XS_PER_CH];  // 19040 B
    __shared__ float ts[TABF];                  // 2304 B

    const int cg = blockIdx.x;      // 0..CG-1
    const int og = blockIdx.y;      // 0..OG-1
    const int b0 = blockIdx.z * NB; // 0 or 2
    const int tid = threadIdx.x;
    const int c0 = cg * NCH;
    const int o0 = og * NO;

    // ---- stage x[b0..b0+1, c0..c0+1, -1..32, -1..32] into LDS (zero-pad) ----
    // Fully unrolled: independent global loads issue back-to-back.
    const float* xb = x + (b0 * C_ + c0) * PIX;
#define STAGE_ONE(IDX)                                                     \
    {                                                                      \
        int _idx = (IDX);                                                  \
        int _bc  = _idx / (XROW * XROW);      /* 0..3 = bb*NCH+ch */       \
        int _rem = _idx - _bc * (XROW * XROW);                             \
        int _bb  = _bc >> 1, _ch = _bc & 1;                                \
        int _r   = _rem / XROW;                                            \
        int _col = _rem - _r * XROW;                                       \
        int _gr = _r - 1, _gc = _col - 1;                                  \
        float _v = 0.f;                                                    \
        if ((unsigned)_gr < (unsigned)H_ && (unsigned)_gc < (unsigned)W_)  \
            _v = xb[(_bb * C_ + _ch) * PIX + _gr * W_ + _gc];              \
        xs[_bc * XS_PER_CH + _r * XSTR + _col] = _v;                       \
    }
#pragma unroll
    for (int k = 0; k < NSTAGE / 256; ++k)       // 18 full passes
        STAGE_ONE(tid + k * 256);
    if (tid < NSTAGE - (NSTAGE / 256) * 256)     // tail: 16 threads
        STAGE_ONE(tid + (NSTAGE / 256) * 256);
#undef STAGE_ONE

    // ---- fused table prep: threads 0..35 sort one (o,t) entry each ----
    if (tid < ENT) {
        const int oo = tid / (NCH * 9);
        const int rem = tid - oo * (NCH * 9);     // 0..17
        const int id = (o0 + oo) * T_ + c0 * 9 + rem;   // global (o,t) entry

        const float* pp = pos + id * P_;
        const float* vv = val + id * P_;
        float p0 = pp[0], p1 = pp[1], p2 = pp[2], p3 = pp[3], p4 = pp[4];
        float v0 = vv[0], v1 = vv[1], v2 = vv[2], v3 = vv[3], v4 = vv[4];

        // 9-CE sorting network for 5 elements, values carried along.
#define CSWAP(a, bb, va, vb)                        \
        {                                           \
            float _pa = fminf(a, bb), _pb = fmaxf(a, bb); \
            bool _sw = (a > bb);                    \
            float _va = _sw ? vb : va;              \
            float _vb = _sw ? va : vb;              \
            a = _pa; bb = _pb; va = _va; vb = _vb;  \
        }
        CSWAP(p0, p1, v0, v1);
        CSWAP(p3, p4, v3, v4);
        CSWAP(p2, p4, v2, v4);
        CSWAP(p2, p3, v2, v3);
        CSWAP(p1, p4, v1, v4);
        CSWAP(p0, p3, v0, v3);
        CSWAP(p0, p2, v0, v2);
        CSWAP(p1, p3, v1, v3);
        CSWAP(p1, p2, v1, v2);
#undef CSWAP

        float inv0 = 1.0f / (p1 - p0 + EPSF);
        float inv1 = 1.0f / (p2 - p1 + EPSF);
        float inv2 = 1.0f / (p3 - p2 + EPSF);
        float inv3 = 1.0f / (p4 - p3 + EPSF);

        float* e = ts + tid * 16;
        e[0]  = inv0;        e[1]  = inv1;        e[2]  = inv2;        e[3]  = inv3;
        e[4]  = -p0 * inv0;  e[5]  = -p1 * inv1;  e[6]  = -p2 * inv2;  e[7]  = -p3 * inv3;
        e[8]  = v1 - v0;     e[9]  = v2 - v1;     e[10] = v3 - v2;     e[11] = v4 - v3;
        e[12] = v0;          e[13] = 0.f;         e[14] = 0.f;         e[15] = 0.f;
    }
    __syncthreads();

    const int r  = tid >> 3;          // 0..31 output row
    const int c4 = (tid & 7) * 4;     // 0,4,...,28 output col base

    // ---- hoisted v0 sums: sv0[oo] = sum over (ch,ij) of v0 (reused per bb) ----
    float sv0[NO];
#pragma unroll
    for (int oo = 0; oo < NO; ++oo) {
        float s = 0.f;
#pragma unroll
        for (int e = 0; e < NCH * 9; ++e)
            s += ts[(oo * NCH * 9 + e) * 16 + 12];
        sv0[oo] = s;
    }

    // ---- EVAL phase: loop over the NB staged batch images, tables reused ----
#pragma unroll
    for (int bb = 0; bb < NB; ++bb) {
        float acc[NO][4];
#pragma unroll
        for (int oo = 0; oo < NO; ++oo)
#pragma unroll
            for (int k = 0; k < 4; ++k)
                acc[oo][k] = sv0[oo];

#pragma unroll
        for (int ch = 0; ch < NCH; ++ch) {
            // x window: padded rows r..r+2, padded cols c4..c4+5 (18 regs)
            float xr[3][6];
#pragma unroll
            for (int i = 0; i < 3; ++i)
#pragma unroll
                for (int j = 0; j < 6; ++j)
                    xr[i][j] = xs[(bb * NCH + ch) * XS_PER_CH + (r + i) * XSTR + c4 + j];

#pragma unroll
            for (int oo = 0; oo < NO; ++oo) {
                const float4* e4 = (const float4*)(ts + (oo * NCH + ch) * 9 * 16);
#pragma unroll
                for (int ij = 0; ij < 9; ++ij) {
                    const int i = ij / 3, j = ij % 3;
                    // uniform-address ds_read_b128 -> LDS broadcast
                    const float4 qi = e4[ij * 4 + 0];   // inv
                    const float4 qf = e4[ij * 4 + 1];   // -p*inv
                    const float4 qd = e4[ij * 4 + 2];   // dv

                    // clamp(t,0,1) via single v_med3_f32 (inputs finite)
#define EVAL(ACC, XV)                                                        \
                    {                                                        \
                        float _xv = (XV);                                    \
                        float _t;                                            \
                        _t = __builtin_amdgcn_fmed3f(fmaf(_xv, qi.x, qf.x), 0.f, 1.f); \
                        ACC = fmaf(_t, qd.x, ACC);                           \
                        _t = __builtin_amdgcn_fmed3f(fmaf(_xv, qi.y, qf.y), 0.f, 1.f); \
                        ACC = fmaf(_t, qd.y, ACC);                           \
                        _t = __builtin_amdgcn_fmed3f(fmaf(_xv, qi.z, qf.z), 0.f, 1.f); \
                        ACC = fmaf(_t, qd.z, ACC);                           \
                        _t = __builtin_amdgcn_fmed3f(fmaf(_xv, qi.w, qf.w), 0.f, 1.f); \
                        ACC = fmaf(_t, qd.w, ACC);                           \
                    }
                    EVAL(acc[oo][0], xr[i][j + 0]);
                    EVAL(acc[oo][1], xr[i][j + 1]);
                    EVAL(acc[oo][2], xr[i][j + 2]);
                    EVAL(acc[oo][3], xr[i][j + 3]);
#undef EVAL
                }
            }
        }

        // coalesced partial writes: addr = 4*tid matches (r*W_ + c4)
#pragma unroll
        for (int oo = 0; oo < NO; ++oo) {
            float4 res;
            res.x = acc[oo][0]; res.y = acc[oo][1];
            res.z = acc[oo][2]; res.w = acc[oo][3];
            float4* pp = (float4*)(part +
                ((size_t)(cg * B_ + b0 + bb) * O_ + o0 + oo) * PIX);
            pp[tid] = res;
        }
    }
}

// Sum the CG partial images: out[j] = sum_cg part[cg][j], float4-vectorized.
__global__ __launch_bounds__(256) void reduce16(
    const float* __restrict__ part, float* __restrict__ out)
{
    int j = blockIdx.x * 256 + threadIdx.x;        // float4 index, 32768 total
    const float4* p4 = (const float4*)part;
    float4 s; s.x = 0.f; s.y = 0.f; s.z = 0.f; s.w = 0.f;
#pragma unroll
    for (int cg = 0; cg < CG; ++cg) {
        float4 p = p4[cg * (B_ * O_ * PIX / 4) + j];
        s.x += p.x; s.y += p.y; s.z += p.z; s.w += p.w;
    }
    ((float4*)out)[j] = s;
}

extern "C" void kernel_launch(void* const* d_in, const int* in_sizes, int n_in,
                              void* d_out, int out_size, void* d_ws, size_t ws_size,
                              hipStream_t stream)
{
    const float* x   = (const float*)d_in[0];
    const float* pos = (const float*)d_in[1];
    const float* val = (const float*)d_in[2];

    float* part = (float*)d_ws;     // CG*B*O*PIX floats = 8 MB

    // Phase 1: fused table-prep + evaluate into per-channel-group partials.
    dim3 grid(CG, OG, BG);
    pw_conv<<<grid, 256, 0, stream>>>(x, pos, val, part);

    // Phase 2: reduce partials into d_out (overwrites poison; no zeroing needed).
    int n4 = B_ * O_ * PIX / 4;     // 32768
    reduce16<<<n4 / 256, 256, 0, stream>>>(part, (float*)d_out);
}

// Round 14
// 78.788 us; speedup vs baseline: 3.3053x; 3.3053x over previous
//
#include <hip/hip_runtime.h>

// Problem constants (from reference setup_inputs)
#define B_  4
#define O_  32
#define C_  32
#define H_  32
#define W_  32
#define P_  5
#define T_  288        // C*3*3
#define PIX (H_ * W_)  // 1024
#define EPSF 1e-6f

#define NCH 2                 // input channels per block
#define CG  (C_ / NCH)        // 16 channel-groups
#define NO  2                 // output channels per block
#define OG  (O_ / NO)         // 16 o-groups

// Per-entry table layout (16 floats, float4 quads):
//   q0 = inv_k = 1/(p[k+1]-p[k]+EPS) (k=0..3); q1 = -p[k]*inv_k;
//   q2 = v[k+1]-v[k]; q3.x = v[0]
#define ENT (NO * NCH * 9)        // 36 entries per block
#define TABF (ENT * 16)           // 576 floats

// x slab: NCH channels, 34x34 halo, row stride 35 (bank pad).
#define XROW 34
#define XSTR 35
#define XS_PER_CH (XROW * XSTR)   // 1190
#define NSTAGE (NCH * XROW * XROW) // 2312 elements to stage

__global__ __launch_bounds__(256, 4) void pw_conv(
    const float* __restrict__ x, const float* __restrict__ pos,
    const float* __restrict__ val, float* __restrict__ part)
{
    __shared__ float xs[NCH * XS_PER_CH];   // 9520 B
    __shared__ float ts[TABF];              // 2304 B

    const int cg = blockIdx.x;      // 0..CG-1
    const int og = blockIdx.y;      // 0..OG-1
    const int b  = blockIdx.z;
    const int tid = threadIdx.x;
    const int c0 = cg * NCH;
    const int o0 = og * NO;

    // ---- stage x[b, c0..c0+NCH-1, -1..32, -1..32] into LDS (zero-padded) ----
    // Fully unrolled: all independent global loads issue before the waits.
    const float* xb = x + (b * C_ + c0) * PIX;
#define STAGE_ONE(IDX)                                                     \
    {                                                                      \
        int _idx = (IDX);                                                  \
        int _ch  = _idx / (XROW * XROW);                                   \
        int _rem = _idx - _ch * (XROW * XROW);                             \
        int _r   = _rem / XROW;                                            \
        int _col = _rem - _r * XROW;                                       \
        int _gr = _r - 1, _gc = _col - 1;                                  \
        float _v = 0.f;                                                    \
        if ((unsigned)_gr < (unsigned)H_ && (unsigned)_gc < (unsigned)W_)  \
            _v = xb[_ch * PIX + _gr * W_ + _gc];                           \
        xs[_ch * XS_PER_CH + _r * XSTR + _col] = _v;                       \
    }
#pragma unroll
    for (int k = 0; k < NSTAGE / 256; ++k)       // 9 full passes
        STAGE_ONE(tid + k * 256);
    if (tid < NSTAGE - (NSTAGE / 256) * 256)     // tail: 8 threads
        STAGE_ONE(tid + (NSTAGE / 256) * 256);
#undef STAGE_ONE

    // ---- fused table prep: threads 0..35 sort one (o,t) entry each ----
    if (tid < ENT) {
        const int oo = tid / (NCH * 9);
        const int rem = tid - oo * (NCH * 9);     // 0..17
        const int id = (o0 + oo) * T_ + c0 * 9 + rem;   // global (o,t) entry

        const float* pp = pos + id * P_;
        const float* vv = val + id * P_;
        float p0 = pp[0], p1 = pp[1], p2 = pp[2], p3 = pp[3], p4 = pp[4];
        float v0 = vv[0], v1 = vv[1], v2 = vv[2], v3 = vv[3], v4 = vv[4];

        // 9-CE sorting network for 5 elements, values carried along.
#define CSWAP(a, bb, va, vb)                        \
        {                                           \
            float _pa = fminf(a, bb), _pb = fmaxf(a, bb); \
            bool _sw = (a > bb);                    \
            float _va = _sw ? vb : va;              \
            float _vb = _sw ? va : vb;              \
            a = _pa; bb = _pb; va = _va; vb = _vb;  \
        }
        CSWAP(p0, p1, v0, v1);
        CSWAP(p3, p4, v3, v4);
        CSWAP(p2, p4, v2, v4);
        CSWAP(p2, p3, v2, v3);
        CSWAP(p1, p4, v1, v4);
        CSWAP(p0, p3, v0, v3);
        CSWAP(p0, p2, v0, v2);
        CSWAP(p1, p3, v1, v3);
        CSWAP(p1, p2, v1, v2);
#undef CSWAP

        float inv0 = 1.0f / (p1 - p0 + EPSF);
        float inv1 = 1.0f / (p2 - p1 + EPSF);
        float inv2 = 1.0f / (p3 - p2 + EPSF);
        float inv3 = 1.0f / (p4 - p3 + EPSF);

        float* e = ts + tid * 16;
        e[0]  = inv0;        e[1]  = inv1;        e[2]  = inv2;        e[3]  = inv3;
        e[4]  = -p0 * inv0;  e[5]  = -p1 * inv1;  e[6]  = -p2 * inv2;  e[7]  = -p3 * inv3;
        e[8]  = v1 - v0;     e[9]  = v2 - v1;     e[10] = v3 - v2;     e[11] = v4 - v3;
        e[12] = v0;          e[13] = 0.f;         e[14] = 0.f;         e[15] = 0.f;
    }
    __syncthreads();

    const int r  = tid >> 3;          // 0..31 output row
    const int c4 = (tid & 7) * 4;     // 0,4,...,28 output col base

    // ---- hoisted v0 sums: sv0[oo] = sum over (ch,ij) of v0 ----
    float sv0[NO];
#pragma unroll
    for (int oo = 0; oo < NO; ++oo) {
        float s = 0.f;
#pragma unroll
        for (int e = 0; e < NCH * 9; ++e)
            s += ts[(oo * NCH * 9 + e) * 16 + 12];
        sv0[oo] = s;
    }

    float acc[NO][4];
#pragma unroll
    for (int oo = 0; oo < NO; ++oo)
#pragma unroll
        for (int k = 0; k < 4; ++k)
            acc[oo][k] = sv0[oo];

#pragma unroll
    for (int ch = 0; ch < NCH; ++ch) {
        // x window: padded rows r..r+2, padded cols c4..c4+5 (18 regs)
        float xr[3][6];
#pragma unroll
        for (int i = 0; i < 3; ++i)
#pragma unroll
            for (int j = 0; j < 6; ++j)
                xr[i][j] = xs[ch * XS_PER_CH + (r + i) * XSTR + c4 + j];

#pragma unroll
        for (int oo = 0; oo < NO; ++oo) {
            const float4* e4 = (const float4*)(ts + (oo * NCH + ch) * 9 * 16);
#pragma unroll
            for (int ij = 0; ij < 9; ++ij) {
                const int i = ij / 3, j = ij % 3;
                // uniform-address ds_read_b128 -> LDS broadcast (conflict-free)
                const float4 qi = e4[ij * 4 + 0];   // inv
                const float4 qf = e4[ij * 4 + 1];   // -p*inv
                const float4 qd = e4[ij * 4 + 2];   // dv

                // clamp(t,0,1) via single v_med3_f32 (inputs provably finite)
#define EVAL(ACC, XV)                                                        \
                {                                                            \
                    float _xv = (XV);                                        \
                    float _t;                                                \
                    _t = __builtin_amdgcn_fmed3f(fmaf(_xv, qi.x, qf.x), 0.f, 1.f); \
                    ACC = fmaf(_t, qd.x, ACC);                               \
                    _t = __builtin_amdgcn_fmed3f(fmaf(_xv, qi.y, qf.y), 0.f, 1.f); \
                    ACC = fmaf(_t, qd.y, ACC);                               \
                    _t = __builtin_amdgcn_fmed3f(fmaf(_xv, qi.z, qf.z), 0.f, 1.f); \
                    ACC = fmaf(_t, qd.z, ACC);                               \
                    _t = __builtin_amdgcn_fmed3f(fmaf(_xv, qi.w, qf.w), 0.f, 1.f); \
                    ACC = fmaf(_t, qd.w, ACC);                               \
                }
                EVAL(acc[oo][0], xr[i][j + 0]);
                EVAL(acc[oo][1], xr[i][j + 1]);
                EVAL(acc[oo][2], xr[i][j + 2]);
                EVAL(acc[oo][3], xr[i][j + 3]);
#undef EVAL
            }
        }
    }

    // coalesced partial writes: addr = 4*tid matches (r*W_ + c4)
#pragma unroll
    for (int oo = 0; oo < NO; ++oo) {
        float4 res;
        res.x = acc[oo][0]; res.y = acc[oo][1];
        res.z = acc[oo][2]; res.w = acc[oo][3];
        float4* pp = (float4*)(part + ((size_t)(cg * B_ + b) * O_ + o0 + oo) * PIX);
        pp[tid] = res;
    }
}

// Sum the CG partial images: out[j] = sum_cg part[cg][j], float4-vectorized.
__global__ __launch_bounds__(256) void reduce16(
    const float* __restrict__ part, float* __restrict__ out)
{
    int j = blockIdx.x * 256 + threadIdx.x;        // float4 index, 32768 total
    const float4* p4 = (const float4*)part;
    float4 s; s.x = 0.f; s.y = 0.f; s.z = 0.f; s.w = 0.f;
#pragma unroll
    for (int cg = 0; cg < CG; ++cg) {
        float4 p = p4[cg * (B_ * O_ * PIX / 4) + j];
        s.x += p.x; s.y += p.y; s.z += p.z; s.w += p.w;
    }
    ((float4*)out)[j] = s;
}

extern "C" void kernel_launch(void* const* d_in, const int* in_sizes, int n_in,
                              void* d_out, int out_size, void* d_ws, size_t ws_size,
                              hipStream_t stream)
{
    const float* x   = (const float*)d_in[0];
    const float* pos = (const float*)d_in[1];
    const float* val = (const float*)d_in[2];

    float* part = (float*)d_ws;     // CG*B*O*PIX floats = 8 MB

    // Phase 1: fused table-prep + evaluate into per-channel-group partials.
    dim3 grid(CG, OG, B_);
    pw_conv<<<grid, 256, 0, stream>>>(x, pos, val, part);

    // Phase 2: reduce partials into d_out (overwrites poison; no zeroing needed).
    int n4 = B_ * O_ * PIX / 4;     // 32768
    reduce16<<<n4 / 256, 256, 0, stream>>>(part, (float*)d_out);
}

// Round 15
// 75.427 us; speedup vs baseline: 3.4526x; 1.0446x over previous
//
#include <hip/hip_runtime.h>

// Problem constants (from reference setup_inputs)
#define B_  4
#define O_  32
#define C_  32
#define H_  32
#define W_  32
#define P_  5
#define T_  288        // C*3*3
#define PIX (H_ * W_)  // 1024
#define EPSF 1e-6f

#define NCH 2                 // input channels per block
#define CG  (C_ / NCH)        // 16 channel-groups
#define NO  2                 // output channels per block (one per wave-pair)
#define OG  (O_ / NO)         // 16 o-groups

// Per-entry table layout (16 floats, float4 quads):
//   q0 = inv_k = 1/(p[k+1]-p[k]+EPS) (k=0..3); q1 = -p[k]*inv_k;
//   q2 = v[k+1]-v[k]; q3.x = v[0]
#define ENT (NO * NCH * 9)        // 36 entries per block
#define TABF (ENT * 16)           // 576 floats

// x slab: NCH channels, 34 rows, stride 36 (16B-aligned cols, 2-way banks = free)
#define XROW 34
#define XSTR 36
#define XS_PER_CH (XROW * XSTR)    // 1224
#define NSTAGE (NCH * XROW * XROW) // 2312 elements to stage

__global__ __launch_bounds__(256, 4) void pw_conv(
    const float* __restrict__ x, const float* __restrict__ pos,
    const float* __restrict__ val, float* __restrict__ part)
{
    __shared__ float xs[NCH * XS_PER_CH];   // 9792 B
    __shared__ float ts[TABF];              // 2304 B

    const int cg = blockIdx.x;      // 0..CG-1
    const int og = blockIdx.y;      // 0..OG-1
    const int b  = blockIdx.z;
    const int tid = threadIdx.x;
    const int c0 = cg * NCH;
    const int o0 = og * NO;

    // ---- stage x[b, c0..c0+NCH-1, -1..32, -1..32] into LDS (zero-padded) ----
    // Fully unrolled: all independent global loads issue before the waits.
    const float* xb = x + (b * C_ + c0) * PIX;
#define STAGE_ONE(IDX)                                                     \
    {                                                                      \
        int _idx = (IDX);                                                  \
        int _ch  = _idx / (XROW * XROW);                                   \
        int _rem = _idx - _ch * (XROW * XROW);                             \
        int _r   = _rem / XROW;                                            \
        int _col = _rem - _r * XROW;                                       \
        int _gr = _r - 1, _gc = _col - 1;                                  \
        float _v = 0.f;                                                    \
        if ((unsigned)_gr < (unsigned)H_ && (unsigned)_gc < (unsigned)W_)  \
            _v = xb[_ch * PIX + _gr * W_ + _gc];                           \
        xs[_ch * XS_PER_CH + _r * XSTR + _col] = _v;                       \
    }
#pragma unroll
    for (int k = 0; k < NSTAGE / 256; ++k)       // 9 full passes
        STAGE_ONE(tid + k * 256);
    if (tid < NSTAGE - (NSTAGE / 256) * 256)     // tail: 8 threads
        STAGE_ONE(tid + (NSTAGE / 256) * 256);
#undef STAGE_ONE

    // ---- fused table prep: threads 0..35 sort one (o,t) entry each ----
    if (tid < ENT) {
        const int oo = tid / (NCH * 9);
        const int rem = tid - oo * (NCH * 9);     // 0..17  (= ch*9 + ij)
        const int id = (o0 + oo) * T_ + c0 * 9 + rem;   // global (o,t) entry

        const float* pp = pos + id * P_;
        const float* vv = val + id * P_;
        float p0 = pp[0], p1 = pp[1], p2 = pp[2], p3 = pp[3], p4 = pp[4];
        float v0 = vv[0], v1 = vv[1], v2 = vv[2], v3 = vv[3], v4 = vv[4];

        // 9-CE sorting network for 5 elements, values carried along.
#define CSWAP(a, bb, va, vb)                        \
        {                                           \
            float _pa = fminf(a, bb), _pb = fmaxf(a, bb); \
            bool _sw = (a > bb);                    \
            float _va = _sw ? vb : va;              \
            float _vb = _sw ? va : vb;              \
            a = _pa; bb = _pb; va = _va; vb = _vb;  \
        }
        CSWAP(p0, p1, v0, v1);
        CSWAP(p3, p4, v3, v4);
        CSWAP(p2, p4, v2, v4);
        CSWAP(p2, p3, v2, v3);
        CSWAP(p1, p4, v1, v4);
        CSWAP(p0, p3, v0, v3);
        CSWAP(p0, p2, v0, v2);
        CSWAP(p1, p3, v1, v3);
        CSWAP(p1, p2, v1, v2);
#undef CSWAP

        float inv0 = 1.0f / (p1 - p0 + EPSF);
        float inv1 = 1.0f / (p2 - p1 + EPSF);
        float inv2 = 1.0f / (p3 - p2 + EPSF);
        float inv3 = 1.0f / (p4 - p3 + EPSF);

        float* e = ts + tid * 16;
        e[0]  = inv0;        e[1]  = inv1;        e[2]  = inv2;        e[3]  = inv3;
        e[4]  = -p0 * inv0;  e[5]  = -p1 * inv1;  e[6]  = -p2 * inv2;  e[7]  = -p3 * inv3;
        e[8]  = v1 - v0;     e[9]  = v2 - v1;     e[10] = v3 - v2;     e[11] = v4 - v3;
        e[12] = v0;          e[13] = 0.f;         e[14] = 0.f;         e[15] = 0.f;
    }
    __syncthreads();

    // ---- output mapping: 1 o x 8 px (2 rows x 4 cols) per thread ----
    // oo = tid>>7 is WAVE-UNIFORM (waves 0-1 -> o0, waves 2-3 -> o0+1):
    // table ds_reads stay uniform-broadcast, but per-thread groups halve.
    const int oo = tid >> 7;
    const int lt = tid & 127;
    const int r0 = (lt >> 3) * 2;     // 0,2,...,30 output row base
    const int c4 = (lt & 7) * 4;      // 0,4,...,28 output col base

    // ---- hoisted v0 sum for this thread's oo ----
    float sv0 = 0.f;
#pragma unroll
    for (int e = 0; e < NCH * 9; ++e)
        sv0 += ts[(oo * NCH * 9 + e) * 16 + 12];

    float acc[2][4];
#pragma unroll
    for (int dr = 0; dr < 2; ++dr)
#pragma unroll
        for (int k = 0; k < 4; ++k)
            acc[dr][k] = sv0;

#pragma unroll
    for (int ch = 0; ch < NCH; ++ch) {
        // x window: rows r0..r0+3 (padded), cols c4..c4+5; float4+float2 loads
        float xw[4][6];
#pragma unroll
        for (int i = 0; i < 4; ++i) {
            const float* base = &xs[ch * XS_PER_CH + (r0 + i) * XSTR + c4];
            float4 q  = *(const float4*)(base);       // 16B-aligned
            float2 q2 = *(const float2*)(base + 4);   // 8B-aligned
            xw[i][0] = q.x;  xw[i][1] = q.y;  xw[i][2] = q.z;  xw[i][3] = q.w;
            xw[i][4] = q2.x; xw[i][5] = q2.y;
        }

        const float4* e4 = (const float4*)(ts + (oo * NCH + ch) * 9 * 16);
#pragma unroll
        for (int ij = 0; ij < 9; ++ij) {
            const int i = ij / 3, j = ij % 3;
            // uniform-address ds_read_b128 -> LDS broadcast (conflict-free)
            const float4 qi = e4[ij * 4 + 0];   // inv
            const float4 qf = e4[ij * 4 + 1];   // -p*inv
            const float4 qd = e4[ij * 4 + 2];   // dv

            // clamp(t,0,1) via single v_med3_f32 (inputs provably finite)
#define EVAL(ACC, XV)                                                        \
            {                                                                \
                float _xv = (XV);                                            \
                float _t;                                                    \
                _t = __builtin_amdgcn_fmed3f(fmaf(_xv, qi.x, qf.x), 0.f, 1.f); \
                ACC = fmaf(_t, qd.x, ACC);                                   \
                _t = __builtin_amdgcn_fmed3f(fmaf(_xv, qi.y, qf.y), 0.f, 1.f); \
                ACC = fmaf(_t, qd.y, ACC);                                   \
                _t = __builtin_amdgcn_fmed3f(fmaf(_xv, qi.z, qf.z), 0.f, 1.f); \
                ACC = fmaf(_t, qd.z, ACC);                                   \
                _t = __builtin_amdgcn_fmed3f(fmaf(_xv, qi.w, qf.w), 0.f, 1.f); \
                ACC = fmaf(_t, qd.w, ACC);                                   \
            }
#pragma unroll
            for (int dr = 0; dr < 2; ++dr) {
                EVAL(acc[dr][0], xw[dr + i][j + 0]);
                EVAL(acc[dr][1], xw[dr + i][j + 1]);
                EVAL(acc[dr][2], xw[dr + i][j + 2]);
                EVAL(acc[dr][3], xw[dr + i][j + 3]);
            }
#undef EVAL
        }
    }

    // coalesced partial writes: two float4 rows per thread
    float* op = part + ((size_t)(cg * B_ + b) * O_ + o0 + oo) * PIX;
#pragma unroll
    for (int dr = 0; dr < 2; ++dr) {
        float4 res;
        res.x = acc[dr][0]; res.y = acc[dr][1];
        res.z = acc[dr][2]; res.w = acc[dr][3];
        *(float4*)(op + (r0 + dr) * W_ + c4) = res;
    }
}

// Sum the CG partial images: out[j] = sum_cg part[cg][j], float4-vectorized.
__global__ __launch_bounds__(256) void reduce16(
    const float* __restrict__ part, float* __restrict__ out)
{
    int j = blockIdx.x * 256 + threadIdx.x;        // float4 index, 32768 total
    const float4* p4 = (const float4*)part;
    float4 s; s.x = 0.f; s.y = 0.f; s.z = 0.f; s.w = 0.f;
#pragma unroll
    for (int cg = 0; cg < CG; ++cg) {
        float4 p = p4[cg * (B_ * O_ * PIX / 4) + j];
        s.x += p.x; s.y += p.y; s.z += p.z; s.w += p.w;
    }
    ((float4*)out)[j] = s;
}

extern "C" void kernel_launch(void* const* d_in, const int* in_sizes, int n_in,
                              void* d_out, int out_size, void* d_ws, size_t ws_size,
                              hipStream_t stream)
{
    const float* x   = (const float*)d_in[0];
    const float* pos = (const float*)d_in[1];
    const float* val = (const float*)d_in[2];

    float* part = (float*)d_ws;     // CG*B*O*PIX floats = 8 MB

    // Phase 1: fused table-prep + evaluate into per-channel-group partials.
    dim3 grid(CG, OG, B_);
    pw_conv<<<grid, 256, 0, stream>>>(x, pos, val, part);

    // Phase 2: reduce partials into d_out (overwrites poison; no zeroing needed).
    int n4 = B_ * O_ * PIX / 4;     // 32768
    reduce16<<<n4 / 256, 256, 0, stream>>>(part, (float*)d_out);
}